// Round 1
// baseline (263.717 us; speedup 1.0000x reference)
//
#include <hip/hip_runtime.h>

#define NPTS 8192   // N
#define NB   4      // B
// channels: Y[pt][0:32)=x1(W1), [32:64)=y2(W2), [64:192)=y3(W3)

// ---------------- Kernel A: Y[pt][c] = Wcat[c] . relu(x[b,:,n]) + bias ----------------
__global__ __launch_bounds__(256) void kA(
    const float* __restrict__ x,
    const float* __restrict__ W1, const float* __restrict__ b1,
    const float* __restrict__ W2, const float* __restrict__ b2,
    const float* __restrict__ W3, const float* __restrict__ b3,
    float* __restrict__ Y)
{
  __shared__ float xt[128][68];               // [in_ch][point], pad 68 (16B-aligned rows)
  const int blk = blockIdx.x;                 // 512 = 4 batches * 128 tiles
  const int b  = blk >> 7;
  const int n0 = (blk & 127) << 6;            // 64 points per block
  const float* xb = x + (size_t)b * 128 * NPTS;

  for (int e = threadIdx.x; e < 128 * 64; e += 256) {
    int i = e >> 6, p = e & 63;
    float v = xb[(size_t)i * NPTS + n0 + p];
    xt[i][p] = fmaxf(v, 0.f);
  }
  __syncthreads();

  const int pg = threadIdx.x & 15;            // 16 point-groups of 4
  const int cg = threadIdx.x >> 4;            // 16 channel-groups, 12 ch each (stride 16)
  const int p0 = pg << 2;

  const float* wrow[12];
  float bias[12];
#pragma unroll
  for (int j = 0; j < 12; ++j) {
    int c = cg + 16 * j;
    if (c < 32)      { wrow[j] = W1 + c * 128;        bias[j] = b1[c]; }
    else if (c < 64) { wrow[j] = W2 + (c - 32) * 128; bias[j] = b2[c - 32]; }
    else             { wrow[j] = W3 + (c - 64) * 128; bias[j] = b3[c - 64]; }
  }

  float acc[12][4] = {};
  for (int i = 0; i < 128; ++i) {
    const float4 xv = *reinterpret_cast<const float4*>(&xt[i][p0]);
#pragma unroll
    for (int j = 0; j < 12; ++j) {
      float wv = wrow[j][i];
      acc[j][0] += wv * xv.x;
      acc[j][1] += wv * xv.y;
      acc[j][2] += wv * xv.z;
      acc[j][3] += wv * xv.w;
    }
  }

#pragma unroll
  for (int pp = 0; pp < 4; ++pp) {
    size_t pt = (size_t)(b * NPTS + n0 + p0 + pp);
#pragma unroll
    for (int j = 0; j < 12; ++j)
      Y[pt * 192 + cg + 16 * j] = acc[j][pp] + bias[j];
  }
}

// ---------------- Kernel B: per-point gather + attention-weight MLP + weighted sum ----
// one wave (64 lanes) per point; 4 points per block
__global__ __launch_bounds__(256) void kB(
    const float* __restrict__ Y, const int* __restrict__ idx,
    const float* __restrict__ Ww1, const float* __restrict__ Ww2,
    const float* __restrict__ bw2, float* __restrict__ mid_ws)
{
  __shared__ int   idxs[4][16];
  __shared__ float g1s[4][32];
  __shared__ float g2s[4][544];   // [o*17+kk], padded
  __shared__ float h2s[4][16];
  __shared__ float wcs[4][272];   // [m*17+kk], padded

  const int w = threadIdx.x >> 6, l = threadIdx.x & 63;
  const int pt = blockIdx.x * 4 + w;            // global point id
  const int bbase = (pt >> 13) << 13;           // b * 8192

  if (l < 16) idxs[w][l] = idx[(size_t)pt * 16 + l];
  __syncthreads();

  // gathers
  if (l < 32) g1s[w][l] = fmaxf(Y[(size_t)pt * 192 + l], 0.f);
#pragma unroll
  for (int t = 0; t < 8; ++t) {
    int e = t * 64 + l, kk = e >> 5, o = e & 31;
    int nb = idxs[w][kk];
    float v = Y[(size_t)(bbase + nb) * 192 + 32 + o];
    g2s[w][o * 17 + kk] = fmaxf(v, 0.f);
  }
  float y3a[16], y3b[16];
#pragma unroll
  for (int kk = 0; kk < 16; ++kk) {
    const float* yr = Y + (size_t)(bbase + idxs[w][kk]) * 192 + 64;
    y3a[kk] = yr[l];
    y3b[kk] = yr[64 + l];
  }
  __syncthreads();

  // h2[m] = relu(Ww1[m] . [g1 | g2flat]); 4 lanes per m
  {
    const int m = l >> 2, j = l & 3;
    const float* wr = Ww1 + m * 544;
    float acc = 0.f;
    for (int c = j * 8; c < j * 8 + 8; ++c) acc += wr[c] * g1s[w][c];
    for (int t = j * 128; t < j * 128 + 128; ++t)
      acc += wr[32 + t] * g2s[w][(t >> 4) * 17 + (t & 15)];
    acc += __shfl_xor(acc, 1);
    acc += __shfl_xor(acc, 2);
    if (j == 0) h2s[w][m] = fmaxf(acc, 0.f);
  }
  __syncthreads();

  // wc[r] = bw2[r] + Ww2[r] . h2   (r = m*16+kk, 256 rows, 4 per lane)
#pragma unroll
  for (int u = 0; u < 4; ++u) {
    int r = l + u * 64;
    float a = bw2[r];
#pragma unroll
    for (int q = 0; q < 16; ++q) a += Ww2[r * 16 + q] * h2s[w][q];
    wcs[w][(r >> 4) * 17 + (r & 15)] = a;
  }
  __syncthreads();

  // mid[c] = relu(sum_k wc[c%16][k] * y3[k][c]); lane l owns c=l and c=l+64
  {
    const float* wc = &wcs[w][(l & 15) * 17];
    float m0 = 0.f, m1 = 0.f;
#pragma unroll
    for (int q = 0; q < 16; ++q) { m0 += wc[q] * y3a[q]; m1 += wc[q] * y3b[q]; }
    mid_ws[(size_t)pt * 128 + l]      = fmaxf(m0, 0.f);
    mid_ws[(size_t)pt * 128 + 64 + l] = fmaxf(m1, 0.f);
  }
}

// ---------------- Kernel C: out = Wout @ mid + bout + x (residual) --------------------
__global__ __launch_bounds__(256) void kC(
    const float* __restrict__ mid_ws,
    const float* __restrict__ Wout, const float* __restrict__ bout,
    const float* __restrict__ x, float* __restrict__ out)
{
  __shared__ float ml[128][68];                 // [mid_ch][point]
  const int blk = blockIdx.x;                   // 512
  const int pt0 = blk << 6;
  const int b  = pt0 >> 13;
  const int n0 = pt0 & (NPTS - 1);

  for (int e = threadIdx.x; e < 64 * 128; e += 256) {
    int p = e >> 7, c = e & 127;
    ml[c][p] = mid_ws[(size_t)(pt0 + p) * 128 + c];
  }
  __syncthreads();

  const int pg = threadIdx.x & 15;
  const int oo = threadIdx.x >> 4;
  const int p0 = pg << 2;
  const int o0 = oo << 3;

  float acc[8][4] = {};
  for (int c = 0; c < 128; ++c) {
    const float4 mv = *reinterpret_cast<const float4*>(&ml[c][p0]);
#pragma unroll
    for (int j = 0; j < 8; ++j) {
      float wv = Wout[(o0 + j) * 128 + c];
      acc[j][0] += wv * mv.x;
      acc[j][1] += wv * mv.y;
      acc[j][2] += wv * mv.z;
      acc[j][3] += wv * mv.w;
    }
  }

#pragma unroll
  for (int j = 0; j < 8; ++j) {
    int o = o0 + j;
    float bo = bout[o];
#pragma unroll
    for (int pp = 0; pp < 4; ++pp) {
      size_t gi = (size_t)(b * 128 + o) * NPTS + (n0 + p0 + pp);
      out[gi] = acc[j][pp] + bo + x[gi];
    }
  }
}

// ---------------- Kernel D: idx -> float (output chunk 2) -----------------------------
__global__ __launch_bounds__(256) void kD(const int* __restrict__ idx,
                                          float* __restrict__ out2)
{
  int e = blockIdx.x * 256 + threadIdx.x;       // 2048 * 256 = 524288 exactly
  out2[e] = (float)idx[e];
}

extern "C" void kernel_launch(void* const* d_in, const int* in_sizes, int n_in,
                              void* d_out, int out_size, void* d_ws, size_t ws_size,
                              hipStream_t stream)
{
  const float* x    = (const float*)d_in[0];
  const int*   idx  = (const int*)  d_in[1];
  const float* W1   = (const float*)d_in[2];
  const float* b1   = (const float*)d_in[3];
  const float* W2   = (const float*)d_in[4];
  const float* b2   = (const float*)d_in[5];
  const float* W3   = (const float*)d_in[6];
  const float* b3   = (const float*)d_in[7];
  const float* Ww1  = (const float*)d_in[8];
  const float* Ww2  = (const float*)d_in[9];
  const float* bw2  = (const float*)d_in[10];
  const float* Wout = (const float*)d_in[11];
  const float* bout = (const float*)d_in[12];

  float* out     = (float*)d_out;
  float* Y       = (float*)d_ws;                        // 32768*192 floats = 25.2 MB
  float* mid     = Y + (size_t)32768 * 192;             // 32768*128 floats = 16.8 MB
  float* out_idx = out + (size_t)NB * 128 * NPTS;       // chunk 2 of d_out

  kA<<<512,  256, 0, stream>>>(x, W1, b1, W2, b2, W3, b3, Y);
  kB<<<8192, 256, 0, stream>>>(Y, idx, Ww1, Ww2, bw2, mid);
  kC<<<512,  256, 0, stream>>>(mid, Wout, bout, x, out);
  kD<<<2048, 256, 0, stream>>>(idx, out_idx);
}

// Round 2
// 208.814 us; speedup vs baseline: 1.2629x; 1.2629x over previous
//
#include <hip/hip_runtime.h>
#include <hip/hip_fp16.h>

#define NPTS   8192
#define NB     4
#define TOTPTS 32768
// Yg layout per point (192 halves):
//   [0:32)   relu(x1)                 (h-MLP input, fp16)
//   [32:64)  relu(y2)                 (h-MLP input, fp16)
//   [64:192) y3 interleaved: half 64+2c = y3[c], 64+2c+1 = y3[c+64]  (raw, fp16)

// ---------------- kT: transpose Ww2 [256][16] -> Ww2T [16][256] -----------------------
__global__ void kT(const float* __restrict__ Ww2, float* __restrict__ Ww2T)
{
  int r = threadIdx.x;            // 256 threads, 1 block
#pragma unroll
  for (int q = 0; q < 16; ++q)
    Ww2T[q * 256 + r] = Ww2[r * 16 + q];
}

// ---------------- kA: Yg[pt] = fused 1x1 convs of relu(x) ----------------------------
__global__ __launch_bounds__(256) void kA(
    const float* __restrict__ x,
    const float* __restrict__ W1, const float* __restrict__ b1,
    const float* __restrict__ W2, const float* __restrict__ b2,
    const float* __restrict__ W3, const float* __restrict__ b3,
    __half* __restrict__ Yg)
{
  __shared__ char smem[34816];                  // xt (34.8KB) then reused as yst (25.6KB)
  float (*xt)[68] = (float(*)[68])smem;         // [in_ch][point]
  __half (*yst)[200] = (__half(*)[200])smem;    // [point][192 padded to 200]

  const int blk = blockIdx.x;                   // 512 = 4 b * 128 tiles
  const int b  = blk >> 7;
  const int n0 = (blk & 127) << 6;
  const float* xb = x + (size_t)b * 128 * NPTS;

  for (int e = threadIdx.x; e < 128 * 64; e += 256) {
    int i = e >> 6, p = e & 63;
    xt[i][p] = fmaxf(xb[(size_t)i * NPTS + n0 + p], 0.f);
  }
  __syncthreads();

  const int pg = threadIdx.x & 15;
  const int cg = threadIdx.x >> 4;
  const int p0 = pg << 2;

  const float* wrow[12];
  float bias[12];
#pragma unroll
  for (int j = 0; j < 12; ++j) {
    int c = cg + 16 * j;
    if (c < 32)      { wrow[j] = W1 + c * 128;        bias[j] = b1[c]; }
    else if (c < 64) { wrow[j] = W2 + (c - 32) * 128; bias[j] = b2[c - 32]; }
    else             { wrow[j] = W3 + (c - 64) * 128; bias[j] = b3[c - 64]; }
  }

  float acc[12][4] = {};
  for (int i = 0; i < 128; ++i) {
    const float4 xv = *reinterpret_cast<const float4*>(&xt[i][p0]);
#pragma unroll
    for (int j = 0; j < 12; ++j) {
      float wv = wrow[j][i];
      acc[j][0] += wv * xv.x;
      acc[j][1] += wv * xv.y;
      acc[j][2] += wv * xv.z;
      acc[j][3] += wv * xv.w;
    }
  }
  __syncthreads();                              // done reading xt; reuse as yst

#pragma unroll
  for (int j = 0; j < 12; ++j) {
    int c = cg + 16 * j;
    int mc;
    if (c < 64) mc = c;
    else { int cc = c - 64; mc = 64 + ((cc < 64) ? 2 * cc : 2 * (cc - 64) + 1); }
#pragma unroll
    for (int pp = 0; pp < 4; ++pp) {
      float v = acc[j][pp] + bias[j];
      if (c < 64) v = fmaxf(v, 0.f);            // pre-relu x1, y2 (h-MLP inputs)
      yst[p0 + pp][mc] = __float2half(v);
    }
  }
  __syncthreads();

  const unsigned* ys32 = (const unsigned*)smem; // yst rows = 100 uints
  unsigned* Yg32 = (unsigned*)(Yg + (size_t)(b * NPTS + n0) * 192); // 96 uints/point
  for (int v = threadIdx.x; v < 64 * 96; v += 256) {
    int p = v / 96, cu = v - p * 96;
    Yg32[p * 96 + cu] = ys32[p * 100 + cu];
  }
}

// ---------------- kB: gather + attention MLP + weighted sum (1 wave / point) ----------
__global__ __launch_bounds__(256) void kB(
    const __half* __restrict__ Yg, const int* __restrict__ idx,
    const float* __restrict__ Ww1, const float* __restrict__ Ww2T,
    const float* __restrict__ bw2, float* __restrict__ mid)
{
  __shared__ float g1s[4][34];
  __shared__ float g2s[4][544];   // [o*17 + kk]
  __shared__ float wcs[4][272];   // [g*17 + q]

  const int w = threadIdx.x >> 6, l = threadIdx.x & 63;
  const int pt = blockIdx.x * 4 + w;
  const int bbase = pt & ~(NPTS - 1);
  const __half* ygp = Yg + (size_t)pt * 192;

  const int idxv = idx[(size_t)pt * 16 + (l & 15)];

  // own-point x1 (pre-relu'd)
  if (l < 16) {
    __half2 v = *reinterpret_cast<const __half2*>(ygp + 2 * l);
    g1s[w][2 * l]     = __low2float(v);
    g1s[w][2 * l + 1] = __high2float(v);
  }
  // y2 gather (pre-relu'd): 4 coalesced half2 loads/lane
#pragma unroll
  for (int t = 0; t < 4; ++t) {
    int p = t * 64 + l;
    int kk = p >> 4, o2 = p & 15;
    int nb = __shfl(idxv, kk);
    __half2 v = *reinterpret_cast<const __half2*>(
        Yg + (size_t)(bbase + nb) * 192 + 32 + 2 * o2);
    g2s[w][(2 * o2) * 17 + kk]     = __low2float(v);
    g2s[w][(2 * o2 + 1) * 17 + kk] = __high2float(v);
  }
  // y3 gather -> registers: lane l holds (y3[l], y3[l+64]) per neighbor
  __half2 y3v[16];
#pragma unroll
  for (int kk = 0; kk < 16; ++kk) {
    int nb = __shfl(idxv, kk);
    y3v[kk] = *reinterpret_cast<const __half2*>(
        Yg + (size_t)(bbase + nb) * 192 + 64 + 2 * l);
  }

  // h[m] = relu(Ww1[m] . a), channel-parallel: lane owns c = 2l + 128t
  float hm[16];
#pragma unroll
  for (int m = 0; m < 16; ++m) hm[m] = 0.f;
#pragma unroll
  for (int t = 0; t < 5; ++t) {
    if (t < 4 || l < 16) {
      int c = 2 * l + 128 * t;
      float a0, a1;
      if (c < 32) { a0 = g1s[w][c]; a1 = g1s[w][c + 1]; }
      else {
        int cc = c - 32;
        int ad = (cc >> 4) * 17 + (cc & 15);
        a0 = g2s[w][ad]; a1 = g2s[w][ad + 1];
      }
#pragma unroll
      for (int m = 0; m < 16; ++m) {
        const float2 wv = *reinterpret_cast<const float2*>(Ww1 + m * 544 + c);
        hm[m] = fmaf(wv.x, a0, fmaf(wv.y, a1, hm[m]));
      }
    }
  }
  // butterfly reduce: all lanes end with full sums
#pragma unroll
  for (int s = 1; s < 64; s <<= 1)
#pragma unroll
    for (int m = 0; m < 16; ++m)
      hm[m] += __shfl_xor(hm[m], s);
#pragma unroll
  for (int m = 0; m < 16; ++m) hm[m] = fmaxf(hm[m], 0.f);

  // wc[r] = bw2[r] + Ww2T[:,r] . h, r = 2l + 128u, coalesced float2 loads
#pragma unroll
  for (int u = 0; u < 2; ++u) {
    int r = 2 * l + 128 * u;
    float2 s = *reinterpret_cast<const float2*>(bw2 + r);
#pragma unroll
    for (int q = 0; q < 16; ++q) {
      const float2 wv = *reinterpret_cast<const float2*>(Ww2T + q * 256 + r);
      s.x = fmaf(wv.x, hm[q], s.x);
      s.y = fmaf(wv.y, hm[q], s.y);
    }
    int g = r >> 4, j = r & 15;                 // j <= 14 (r even)
    wcs[w][g * 17 + j]     = s.x;
    wcs[w][g * 17 + j + 1] = s.y;
  }

  // mid[c] = relu(sum_k wc[c&15][k] * y3[k][c]); lane owns c = l, l+64 (same group)
  const float* wrow = &wcs[w][(l & 15) * 17];
  float m0 = 0.f, m1 = 0.f;
#pragma unroll
  for (int q = 0; q < 16; ++q) {
    float2 y = __half22float2(y3v[q]);
    m0 = fmaf(wrow[q], y.x, m0);
    m1 = fmaf(wrow[q], y.y, m1);
  }
  mid[(size_t)pt * 128 + l]      = fmaxf(m0, 0.f);
  mid[(size_t)pt * 128 + 64 + l] = fmaxf(m1, 0.f);
}

// ---------------- kC: out = Wout @ mid + bout + x (residual) --------------------------
__global__ __launch_bounds__(256) void kC(
    const float* __restrict__ mid_ws,
    const float* __restrict__ Wout, const float* __restrict__ bout,
    const float* __restrict__ x, float* __restrict__ out)
{
  __shared__ float ml[128][68];
  const int blk = blockIdx.x;
  const int pt0 = blk << 6;
  const int b  = pt0 >> 13;
  const int n0 = pt0 & (NPTS - 1);

  for (int e = threadIdx.x; e < 64 * 128; e += 256) {
    int p = e >> 7, c = e & 127;
    ml[c][p] = mid_ws[(size_t)(pt0 + p) * 128 + c];
  }
  __syncthreads();

  const int pg = threadIdx.x & 15;
  const int oo = threadIdx.x >> 4;
  const int p0 = pg << 2;
  const int o0 = oo << 3;

  float acc[8][4] = {};
  for (int c = 0; c < 128; ++c) {
    const float4 mv = *reinterpret_cast<const float4*>(&ml[c][p0]);
#pragma unroll
    for (int j = 0; j < 8; ++j) {
      float wv = Wout[(o0 + j) * 128 + c];
      acc[j][0] += wv * mv.x;
      acc[j][1] += wv * mv.y;
      acc[j][2] += wv * mv.z;
      acc[j][3] += wv * mv.w;
    }
  }

#pragma unroll
  for (int j = 0; j < 8; ++j) {
    int o = o0 + j;
    float bo = bout[o];
#pragma unroll
    for (int pp = 0; pp < 4; ++pp) {
      size_t gi = (size_t)(b * 128 + o) * NPTS + (n0 + p0 + pp);
      out[gi] = acc[j][pp] + bo + x[gi];
    }
  }
}

// ---------------- kD: idx -> float --------------------------------------------------
__global__ __launch_bounds__(256) void kD(const int* __restrict__ idx,
                                          float* __restrict__ out2)
{
  int e = blockIdx.x * 256 + threadIdx.x;
  out2[e] = (float)idx[e];
}

extern "C" void kernel_launch(void* const* d_in, const int* in_sizes, int n_in,
                              void* d_out, int out_size, void* d_ws, size_t ws_size,
                              hipStream_t stream)
{
  const float* x    = (const float*)d_in[0];
  const int*   idx  = (const int*)  d_in[1];
  const float* W1   = (const float*)d_in[2];
  const float* b1   = (const float*)d_in[3];
  const float* W2   = (const float*)d_in[4];
  const float* b2   = (const float*)d_in[5];
  const float* W3   = (const float*)d_in[6];
  const float* b3   = (const float*)d_in[7];
  const float* Ww1  = (const float*)d_in[8];
  const float* Ww2  = (const float*)d_in[9];
  const float* bw2  = (const float*)d_in[10];
  const float* Wout = (const float*)d_in[11];
  const float* bout = (const float*)d_in[12];

  float* out     = (float*)d_out;
  __half* Yg     = (__half*)d_ws;                               // 12.58 MB
  float* mid     = (float*)((char*)d_ws + (size_t)TOTPTS * 192 * 2);
  float* Ww2T    = mid + (size_t)TOTPTS * 128;                  // 16 KB
  float* out_idx = out + (size_t)NB * 128 * NPTS;

  kT<<<1,    256, 0, stream>>>(Ww2, Ww2T);
  kA<<<512,  256, 0, stream>>>(x, W1, b1, W2, b2, W3, b3, Yg);
  kB<<<8192, 256, 0, stream>>>(Yg, idx, Ww1, Ww2T, bw2, mid);
  kC<<<512,  256, 0, stream>>>(mid, Wout, bout, x, out);
  kD<<<2048, 256, 0, stream>>>(idx, out_idx);
}

// Round 3
// 164.764 us; speedup vs baseline: 1.6006x; 1.2673x over previous
//
#include <hip/hip_runtime.h>
#include <hip/hip_fp16.h>

#define NPTS    8192
#define NB      4
#define TOTPTS  32768
#define VSTRIDE 288   // floats per point in V: [u(16) | v(kk*16+m, 256) | pad(16)]
// Yg layout per point (192 halves):
//   [0:32)   relu(x1)   [32:64) relu(y2)   (kV inputs, fp16)
//   [64:192) y3 interleaved: half 64+2c = y3[c], 64+2c+1 = y3[c+64]

// ---------------- kT: transpose Ww2 [256][16] -> Ww2T [16][256] -----------------------
__global__ void kT(const float* __restrict__ Ww2, float* __restrict__ Ww2T)
{
  int r = threadIdx.x;
#pragma unroll
  for (int q = 0; q < 16; ++q)
    Ww2T[q * 256 + r] = Ww2[r * 16 + q];
}

// ---------------- kA: Yg[pt] = fused 1x1 convs of relu(x) ----------------------------
__global__ __launch_bounds__(256) void kA(
    const float* __restrict__ x,
    const float* __restrict__ W1, const float* __restrict__ b1,
    const float* __restrict__ W2, const float* __restrict__ b2,
    const float* __restrict__ W3, const float* __restrict__ b3,
    __half* __restrict__ Yg)
{
  __shared__ char smem[34816];
  float (*xt)[68] = (float(*)[68])smem;
  __half (*yst)[200] = (__half(*)[200])smem;

  const int blk = blockIdx.x;                   // 512
  const int b  = blk >> 7;
  const int n0 = (blk & 127) << 6;
  const float* xb = x + (size_t)b * 128 * NPTS;

  for (int e = threadIdx.x; e < 128 * 64; e += 256) {
    int i = e >> 6, p = e & 63;
    xt[i][p] = fmaxf(xb[(size_t)i * NPTS + n0 + p], 0.f);
  }
  __syncthreads();

  const int pg = threadIdx.x & 15;
  const int cg = threadIdx.x >> 4;
  const int p0 = pg << 2;

  const float* wrow[12];
  float bias[12];
#pragma unroll
  for (int j = 0; j < 12; ++j) {
    int c = cg + 16 * j;
    if (c < 32)      { wrow[j] = W1 + c * 128;        bias[j] = b1[c]; }
    else if (c < 64) { wrow[j] = W2 + (c - 32) * 128; bias[j] = b2[c - 32]; }
    else             { wrow[j] = W3 + (c - 64) * 128; bias[j] = b3[c - 64]; }
  }

  float acc[12][4] = {};
  for (int i = 0; i < 128; ++i) {
    const float4 xv = *reinterpret_cast<const float4*>(&xt[i][p0]);
#pragma unroll
    for (int j = 0; j < 12; ++j) {
      float wv = wrow[j][i];
      acc[j][0] += wv * xv.x;
      acc[j][1] += wv * xv.y;
      acc[j][2] += wv * xv.z;
      acc[j][3] += wv * xv.w;
    }
  }
  __syncthreads();

#pragma unroll
  for (int j = 0; j < 12; ++j) {
    int c = cg + 16 * j;
    int mc;
    if (c < 64) mc = c;
    else { int cc = c - 64; mc = 64 + ((cc < 64) ? 2 * cc : 2 * (cc - 64) + 1); }
#pragma unroll
    for (int pp = 0; pp < 4; ++pp) {
      float v = acc[j][pp] + bias[j];
      if (c < 64) v = fmaxf(v, 0.f);
      yst[p0 + pp][mc] = __float2half(v);
    }
  }
  __syncthreads();

  const unsigned* ys32 = (const unsigned*)smem;
  unsigned* Yg32 = (unsigned*)(Yg + (size_t)(b * NPTS + n0) * 192);
  for (int v = threadIdx.x; v < 64 * 96; v += 256) {
    int p = v / 96, cu = v - p * 96;
    Yg32[p * 96 + cu] = ys32[p * 100 + cu];
  }
}

// ---------------- kV: per-point u,v precompute (h-GEMM pushed before the gather) ------
// u[m]      = Ww1[m][0:32) . relu(x1)
// v[kk][m]  = sum_o Ww1[m][32+o*16+kk] . relu(y2[o])
__global__ __launch_bounds__(256) void kV(
    const __half* __restrict__ Yg, const float* __restrict__ Ww1,
    float* __restrict__ V)
{
  __shared__ float a_lds[64][66];
  __shared__ float v_lds[64][148];
  const int t = threadIdx.x;
  const int w = __builtin_amdgcn_readfirstlane(t >> 6);
  const int l = t & 63;
  const int pt0 = blockIdx.x * 64;

  // stage relu(x1)|relu(y2) (64 halves/pt) -> fp32 LDS
  const unsigned* Yg32 = (const unsigned*)Yg + (size_t)pt0 * 96;
#pragma unroll
  for (int i = 0; i < 8; ++i) {
    int e = t + 256 * i;
    int p = e >> 5, cu = e & 31;
    unsigned uu = Yg32[(size_t)p * 96 + cu];
    __half2 hv = *reinterpret_cast<const __half2*>(&uu);
    a_lds[p][2 * cu]     = __low2float(hv);
    a_lds[p][2 * cu + 1] = __high2float(hv);
  }
  __syncthreads();

  const int p = l;
  // u rows m = 4w+e
  {
    float acc[4] = {};
    for (int c = 0; c < 32; ++c) {
      float a = a_lds[p][c];
#pragma unroll
      for (int e = 0; e < 4; ++e)
        acc[e] = fmaf(Ww1[(4 * w + e) * 544 + c], a, acc[e]);
    }
#pragma unroll
    for (int e = 0; e < 4; ++e) v_lds[p][4 * w + e] = acc[e];
  }

  float ay[32];
#pragma unroll
  for (int o = 0; o < 32; ++o) ay[o] = a_lds[p][32 + o];

  // pass A: kk = 0..7
  {
    float acc[8][4] = {};
#pragma unroll 4
    for (int o = 0; o < 32; ++o) {
      float a = ay[o];
#pragma unroll
      for (int kk = 0; kk < 8; ++kk)
#pragma unroll
        for (int e = 0; e < 4; ++e)
          acc[kk][e] = fmaf(Ww1[(4 * w + e) * 544 + 32 + o * 16 + kk], a, acc[kk][e]);
    }
#pragma unroll
    for (int kk = 0; kk < 8; ++kk)
#pragma unroll
      for (int e = 0; e < 4; ++e)
        v_lds[p][16 + kk * 16 + 4 * w + e] = acc[kk][e];
  }
  __syncthreads();
  // copy out floats [0,144) of each point
#pragma unroll
  for (int i = 0; i < 36; ++i) {
    int e = t + 256 * i;                 // 9216 = 64*144
    int pp = e / 144, f = e - pp * 144;
    V[(size_t)(pt0 + pp) * VSTRIDE + f] = v_lds[pp][f];
  }
  __syncthreads();

  // pass B: kk = 8..15
  {
    float acc[8][4] = {};
#pragma unroll 4
    for (int o = 0; o < 32; ++o) {
      float a = ay[o];
#pragma unroll
      for (int k2 = 0; k2 < 8; ++k2)
#pragma unroll
        for (int e = 0; e < 4; ++e)
          acc[k2][e] = fmaf(Ww1[(4 * w + e) * 544 + 32 + o * 16 + 8 + k2], a, acc[k2][e]);
    }
#pragma unroll
    for (int k2 = 0; k2 < 8; ++k2)
#pragma unroll
      for (int e = 0; e < 4; ++e)
        v_lds[p][k2 * 16 + 4 * w + e] = acc[k2][e];
  }
  __syncthreads();
#pragma unroll
  for (int i = 0; i < 32; ++i) {
    int e = t + 256 * i;                 // 8192 = 64*128
    int pp = e >> 7, f = e & 127;
    V[(size_t)(pt0 + pp) * VSTRIDE + 144 + f] = v_lds[pp][f];
  }
}

// ---------------- kB: gather + attention weights + weighted sum (1 wave / point) ------
__global__ __launch_bounds__(256) void kB(
    const float* __restrict__ V, const __half* __restrict__ Yg,
    const int* __restrict__ idx, const float* __restrict__ Ww2T,
    const float* __restrict__ bw2, float* __restrict__ mid,
    float* __restrict__ out_idx)
{
  __shared__ float wcs[4][272];
  __shared__ float hs[4][16];

  const int w = threadIdx.x >> 6, l = threadIdx.x & 63;
  const int pt = blockIdx.x * 4 + w;
  const int bbase = pt & ~(NPTS - 1);
  const int kk = l >> 2, j = l & 3;

  const int idxv = idx[(size_t)pt * 16 + (l & 15)];
  if (l < 16) out_idx[(size_t)pt * 16 + l] = (float)idxv;   // fused idx->float output

  // h = relu(u + sum_kk v[nb_kk])
  const float4* V4 = (const float4*)V;
  float4 h4 = V4[(size_t)pt * 72 + j];                       // u[4j..4j+3]
  int nb = __shfl(idxv, kk);
  float4 vv = V4[(size_t)(bbase + nb) * 72 + 4 + kk * 4 + j];
  h4.x += vv.x; h4.y += vv.y; h4.z += vv.z; h4.w += vv.w;
#pragma unroll
  for (int s = 4; s < 64; s <<= 1) {
    h4.x += __shfl_xor(h4.x, s);
    h4.y += __shfl_xor(h4.y, s);
    h4.z += __shfl_xor(h4.z, s);
    h4.w += __shfl_xor(h4.w, s);
  }
  if (l < 4) {
    hs[w][4 * l + 0] = fmaxf(h4.x, 0.f);
    hs[w][4 * l + 1] = fmaxf(h4.y, 0.f);
    hs[w][4 * l + 2] = fmaxf(h4.z, 0.f);
    hs[w][4 * l + 3] = fmaxf(h4.w, 0.f);
  }

  // y3 gather -> registers: lane l holds (y3[l], y3[l+64]) per neighbor
  __half2 y3v[16];
#pragma unroll
  for (int k2 = 0; k2 < 16; ++k2) {
    int nb2 = __shfl(idxv, k2);
    y3v[k2] = *reinterpret_cast<const __half2*>(
        Yg + (size_t)(bbase + nb2) * 192 + 64 + 2 * l);
  }

  // wc[r] = bw2[r] + Ww2T[:,r] . h, r = 2l + 128u, coalesced float2 loads
#pragma unroll
  for (int u2 = 0; u2 < 2; ++u2) {
    int r = 2 * l + 128 * u2;
    float2 s2 = *reinterpret_cast<const float2*>(bw2 + r);
#pragma unroll
    for (int q = 0; q < 16; ++q) {
      const float2 wv = *reinterpret_cast<const float2*>(Ww2T + q * 256 + r);
      float hq = hs[w][q];
      s2.x = fmaf(wv.x, hq, s2.x);
      s2.y = fmaf(wv.y, hq, s2.y);
    }
    int g = r >> 4, jj = r & 15;
    wcs[w][g * 17 + jj]     = s2.x;
    wcs[w][g * 17 + jj + 1] = s2.y;
  }

  // mid[c] = relu(sum_k wc[c&15][k] * y3[k][c]); lane owns c = l, l+64
  const float* wrow = &wcs[w][(l & 15) * 17];
  float m0 = 0.f, m1 = 0.f;
#pragma unroll
  for (int q = 0; q < 16; ++q) {
    float2 y = __half22float2(y3v[q]);
    m0 = fmaf(wrow[q], y.x, m0);
    m1 = fmaf(wrow[q], y.y, m1);
  }
  mid[(size_t)pt * 128 + l]      = fmaxf(m0, 0.f);
  mid[(size_t)pt * 128 + 64 + l] = fmaxf(m1, 0.f);
}

// ---------------- kC: out = Wout @ mid + bout + x (residual) --------------------------
__global__ __launch_bounds__(256) void kC(
    const float* __restrict__ mid_ws,
    const float* __restrict__ Wout, const float* __restrict__ bout,
    const float* __restrict__ x, float* __restrict__ out)
{
  __shared__ float ml[128][68];
  const int blk = blockIdx.x;
  const int pt0 = blk << 6;
  const int b  = pt0 >> 13;
  const int n0 = pt0 & (NPTS - 1);

  for (int e = threadIdx.x; e < 64 * 128; e += 256) {
    int p = e >> 7, c = e & 127;
    ml[c][p] = mid_ws[(size_t)(pt0 + p) * 128 + c];
  }
  __syncthreads();

  const int pg = threadIdx.x & 15;
  const int oo = threadIdx.x >> 4;
  const int p0 = pg << 2;
  const int o0 = oo << 3;

  float acc[8][4] = {};
  for (int c = 0; c < 128; ++c) {
    const float4 mv = *reinterpret_cast<const float4*>(&ml[c][p0]);
#pragma unroll
    for (int jj = 0; jj < 8; ++jj) {
      float wv = Wout[(o0 + jj) * 128 + c];
      acc[jj][0] += wv * mv.x;
      acc[jj][1] += wv * mv.y;
      acc[jj][2] += wv * mv.z;
      acc[jj][3] += wv * mv.w;
    }
  }

#pragma unroll
  for (int jj = 0; jj < 8; ++jj) {
    int o = o0 + jj;
    float bo = bout[o];
#pragma unroll
    for (int pp = 0; pp < 4; ++pp) {
      size_t gi = (size_t)(b * 128 + o) * NPTS + (n0 + p0 + pp);
      out[gi] = acc[jj][pp] + bo + x[gi];
    }
  }
}

extern "C" void kernel_launch(void* const* d_in, const int* in_sizes, int n_in,
                              void* d_out, int out_size, void* d_ws, size_t ws_size,
                              hipStream_t stream)
{
  const float* x    = (const float*)d_in[0];
  const int*   idx  = (const int*)  d_in[1];
  const float* W1   = (const float*)d_in[2];
  const float* b1   = (const float*)d_in[3];
  const float* W2   = (const float*)d_in[4];
  const float* b2   = (const float*)d_in[5];
  const float* W3   = (const float*)d_in[6];
  const float* b3   = (const float*)d_in[7];
  const float* Ww1  = (const float*)d_in[8];
  const float* Ww2  = (const float*)d_in[9];
  const float* bw2  = (const float*)d_in[10];
  const float* Wout = (const float*)d_in[11];
  const float* bout = (const float*)d_in[12];

  float* out     = (float*)d_out;
  __half* Yg     = (__half*)d_ws;                                   // 12.58 MB
  float* mid     = (float*)((char*)d_ws + (size_t)TOTPTS * 192 * 2);// 16.78 MB
  float* Ww2T    = mid + (size_t)TOTPTS * 128;                      // 16 KB
  float* V       = Ww2T + 16 * 256;                                 // 37.75 MB
  float* out_idx = out + (size_t)NB * 128 * NPTS;

  kT<<<1,    256, 0, stream>>>(Ww2, Ww2T);
  kA<<<512,  256, 0, stream>>>(x, W1, b1, W2, b2, W3, b3, Yg);
  kV<<<512,  256, 0, stream>>>(Yg, Ww1, V);
  kB<<<8192, 256, 0, stream>>>(V, Yg, idx, Ww2T, bw2, mid, out_idx);
  kC<<<512,  256, 0, stream>>>(mid, Wout, bout, x, out);
}

// Round 4
// 164.377 us; speedup vs baseline: 1.6043x; 1.0024x over previous
//
#include <hip/hip_runtime.h>
#include <hip/hip_fp16.h>

#define NPTS    8192
#define NB      4
#define TOTPTS  32768
#define VSTRIDE 288   // floats per point in V: [u(16) | v(kk*16+m, 256) | pad(16)]
// Yg layout per point (192 halves):
//   [0:32)   relu(x1)   [32:64) relu(y2)   (kV inputs, fp16)
//   [64:192) y3 interleaved: half 64+2c = y3[c], 64+2c+1 = y3[c+64]

// ---------------- kT: transpose Ww2 [256][16] -> Ww2T [16][256] -----------------------
__global__ void kT(const float* __restrict__ Ww2, float* __restrict__ Ww2T)
{
  int r = threadIdx.x;
#pragma unroll
  for (int q = 0; q < 16; ++q)
    Ww2T[q * 256 + r] = Ww2[r * 16 + q];
}

// ---------------- kA: Yg[pt] = fused 1x1 convs of relu(x) ----------------------------
__global__ __launch_bounds__(256) void kA(
    const float* __restrict__ x,
    const float* __restrict__ W1, const float* __restrict__ b1,
    const float* __restrict__ W2, const float* __restrict__ b2,
    const float* __restrict__ W3, const float* __restrict__ b3,
    __half* __restrict__ Yg)
{
  __shared__ char smem[34816];
  float (*xt)[68] = (float(*)[68])smem;
  __half (*yst)[200] = (__half(*)[200])smem;

  const int blk = blockIdx.x;                   // 512
  const int b  = blk >> 7;
  const int n0 = (blk & 127) << 6;
  const float* xb = x + (size_t)b * 128 * NPTS;

  for (int e = threadIdx.x; e < 128 * 64; e += 256) {
    int i = e >> 6, p = e & 63;
    xt[i][p] = fmaxf(xb[(size_t)i * NPTS + n0 + p], 0.f);
  }
  __syncthreads();

  const int pg = threadIdx.x & 15;
  const int cg = threadIdx.x >> 4;
  const int p0 = pg << 2;

  const float* wrow[12];
  float bias[12];
#pragma unroll
  for (int j = 0; j < 12; ++j) {
    int c = cg + 16 * j;
    if (c < 32)      { wrow[j] = W1 + c * 128;        bias[j] = b1[c]; }
    else if (c < 64) { wrow[j] = W2 + (c - 32) * 128; bias[j] = b2[c - 32]; }
    else             { wrow[j] = W3 + (c - 64) * 128; bias[j] = b3[c - 64]; }
  }

  float acc[12][4] = {};
  for (int i = 0; i < 128; ++i) {
    const float4 xv = *reinterpret_cast<const float4*>(&xt[i][p0]);
#pragma unroll
    for (int j = 0; j < 12; ++j) {
      float wv = wrow[j][i];
      acc[j][0] += wv * xv.x;
      acc[j][1] += wv * xv.y;
      acc[j][2] += wv * xv.z;
      acc[j][3] += wv * xv.w;
    }
  }
  __syncthreads();

#pragma unroll
  for (int j = 0; j < 12; ++j) {
    int c = cg + 16 * j;
    int mc;
    if (c < 64) mc = c;
    else { int cc = c - 64; mc = 64 + ((cc < 64) ? 2 * cc : 2 * (cc - 64) + 1); }
#pragma unroll
    for (int pp = 0; pp < 4; ++pp) {
      float v = acc[j][pp] + bias[j];
      if (c < 64) v = fmaxf(v, 0.f);
      yst[p0 + pp][mc] = __float2half(v);
    }
  }
  __syncthreads();

  const unsigned* ys32 = (const unsigned*)smem;
  unsigned* Yg32 = (unsigned*)(Yg + (size_t)(b * NPTS + n0) * 192);
  for (int v = threadIdx.x; v < 64 * 96; v += 256) {
    int p = v / 96, cu = v - p * 96;
    Yg32[p * 96 + cu] = ys32[p * 100 + cu];
  }
}

// ---------------- kV: per-point u,v precompute (h-GEMM pushed before the gather) ------
// u[m]      = Ww1[m][0:32) . relu(x1)
// v[kk][m]  = sum_o Ww1[m][32+o*16+kk] . relu(y2[o])
__global__ __launch_bounds__(256) void kV(
    const __half* __restrict__ Yg, const float* __restrict__ Ww1,
    float* __restrict__ V)
{
  __shared__ float a_lds[64][66];
  __shared__ float v_lds[64][148];
  const int t = threadIdx.x;
  const int w = __builtin_amdgcn_readfirstlane(t >> 6);
  const int l = t & 63;
  const int pt0 = blockIdx.x * 64;

  // stage relu(x1)|relu(y2) (64 halves/pt) -> fp32 LDS
  const unsigned* Yg32 = (const unsigned*)Yg + (size_t)pt0 * 96;
#pragma unroll
  for (int i = 0; i < 8; ++i) {
    int e = t + 256 * i;
    int p = e >> 5, cu = e & 31;
    unsigned uu = Yg32[(size_t)p * 96 + cu];
    __half2 hv = *reinterpret_cast<const __half2*>(&uu);
    a_lds[p][2 * cu]     = __low2float(hv);
    a_lds[p][2 * cu + 1] = __high2float(hv);
  }
  __syncthreads();

  const int p = l;
  // u rows m = 4w+e
  {
    float acc[4] = {};
    for (int c = 0; c < 32; ++c) {
      float a = a_lds[p][c];
#pragma unroll
      for (int e = 0; e < 4; ++e)
        acc[e] = fmaf(Ww1[(4 * w + e) * 544 + c], a, acc[e]);
    }
#pragma unroll
    for (int e = 0; e < 4; ++e) v_lds[p][4 * w + e] = acc[e];
  }

  float ay[32];
#pragma unroll
  for (int o = 0; o < 32; ++o) ay[o] = a_lds[p][32 + o];

  // pass A: kk = 0..7
  {
    float acc[8][4] = {};
#pragma unroll 4
    for (int o = 0; o < 32; ++o) {
      float a = ay[o];
#pragma unroll
      for (int kk = 0; kk < 8; ++kk)
#pragma unroll
        for (int e = 0; e < 4; ++e)
          acc[kk][e] = fmaf(Ww1[(4 * w + e) * 544 + 32 + o * 16 + kk], a, acc[kk][e]);
    }
#pragma unroll
    for (int kk = 0; kk < 8; ++kk)
#pragma unroll
      for (int e = 0; e < 4; ++e)
        v_lds[p][16 + kk * 16 + 4 * w + e] = acc[kk][e];
  }
  __syncthreads();
  // copy out floats [0,144) of each point
#pragma unroll
  for (int i = 0; i < 36; ++i) {
    int e = t + 256 * i;                 // 9216 = 64*144
    int pp = e / 144, f = e - pp * 144;
    V[(size_t)(pt0 + pp) * VSTRIDE + f] = v_lds[pp][f];
  }
  __syncthreads();

  // pass B: kk = 8..15
  {
    float acc[8][4] = {};
#pragma unroll 4
    for (int o = 0; o < 32; ++o) {
      float a = ay[o];
#pragma unroll
      for (int k2 = 0; k2 < 8; ++k2)
#pragma unroll
        for (int e = 0; e < 4; ++e)
          acc[k2][e] = fmaf(Ww1[(4 * w + e) * 544 + 32 + o * 16 + 8 + k2], a, acc[k2][e]);
    }
#pragma unroll
    for (int k2 = 0; k2 < 8; ++k2)
#pragma unroll
      for (int e = 0; e < 4; ++e)
        v_lds[p][k2 * 16 + 4 * w + e] = acc[k2][e];
  }
  __syncthreads();
#pragma unroll
  for (int i = 0; i < 32; ++i) {
    int e = t + 256 * i;                 // 8192 = 64*128
    int pp = e >> 7, f = e & 127;
    V[(size_t)(pt0 + pp) * VSTRIDE + 144 + f] = v_lds[pp][f];
  }
}

// ---------------- kB: gather + attention weights + weighted sum (1 wave / point) ------
__global__ __launch_bounds__(256) void kB(
    const float* __restrict__ V, const __half* __restrict__ Yg,
    const int* __restrict__ idx, const float* __restrict__ Ww2T,
    const float* __restrict__ bw2, float* __restrict__ mid,
    float* __restrict__ out_idx)
{
  __shared__ float wcs[4][272];
  __shared__ float hs[4][16];

  const int w = threadIdx.x >> 6, l = threadIdx.x & 63;
  const int pt = blockIdx.x * 4 + w;
  const int bbase = pt & ~(NPTS - 1);
  const int kk = l >> 2, j = l & 3;

  const int idxv = idx[(size_t)pt * 16 + (l & 15)];
  if (l < 16) out_idx[(size_t)pt * 16 + l] = (float)idxv;   // fused idx->float output

  // h = relu(u + sum_kk v[nb_kk])
  const float4* V4 = (const float4*)V;
  float4 h4 = V4[(size_t)pt * 72 + j];                       // u[4j..4j+3]
  int nb = __shfl(idxv, kk);
  float4 vv = V4[(size_t)(bbase + nb) * 72 + 4 + kk * 4 + j];
  h4.x += vv.x; h4.y += vv.y; h4.z += vv.z; h4.w += vv.w;
#pragma unroll
  for (int s = 4; s < 64; s <<= 1) {
    h4.x += __shfl_xor(h4.x, s);
    h4.y += __shfl_xor(h4.y, s);
    h4.z += __shfl_xor(h4.z, s);
    h4.w += __shfl_xor(h4.w, s);
  }
  if (l < 4) {
    hs[w][4 * l + 0] = fmaxf(h4.x, 0.f);
    hs[w][4 * l + 1] = fmaxf(h4.y, 0.f);
    hs[w][4 * l + 2] = fmaxf(h4.z, 0.f);
    hs[w][4 * l + 3] = fmaxf(h4.w, 0.f);
  }

  // y3 gather -> registers: lane l holds (y3[l], y3[l+64]) per neighbor
  __half2 y3v[16];
#pragma unroll
  for (int k2 = 0; k2 < 16; ++k2) {
    int nb2 = __shfl(idxv, k2);
    y3v[k2] = *reinterpret_cast<const __half2*>(
        Yg + (size_t)(bbase + nb2) * 192 + 64 + 2 * l);
  }

  // wc[r] = bw2[r] + Ww2T[:,r] . h, r = 2l + 128u, coalesced float2 loads
#pragma unroll
  for (int u2 = 0; u2 < 2; ++u2) {
    int r = 2 * l + 128 * u2;
    float2 s2 = *reinterpret_cast<const float2*>(bw2 + r);
#pragma unroll
    for (int q = 0; q < 16; ++q) {
      const float2 wv = *reinterpret_cast<const float2*>(Ww2T + q * 256 + r);
      float hq = hs[w][q];
      s2.x = fmaf(wv.x, hq, s2.x);
      s2.y = fmaf(wv.y, hq, s2.y);
    }
    int g = r >> 4, jj = r & 15;
    wcs[w][g * 17 + jj]     = s2.x;
    wcs[w][g * 17 + jj + 1] = s2.y;
  }

  // mid[c] = relu(sum_k wc[c&15][k] * y3[k][c]); lane owns c = l, l+64
  const float* wrow = &wcs[w][(l & 15) * 17];
  float m0 = 0.f, m1 = 0.f;
#pragma unroll
  for (int q = 0; q < 16; ++q) {
    float2 y = __half22float2(y3v[q]);
    m0 = fmaf(wrow[q], y.x, m0);
    m1 = fmaf(wrow[q], y.y, m1);
  }
  mid[(size_t)pt * 128 + l]      = fmaxf(m0, 0.f);
  mid[(size_t)pt * 128 + 64 + l] = fmaxf(m1, 0.f);
}

// ---------------- kC: out = Wout @ mid + bout + x (residual) --------------------------
__global__ __launch_bounds__(256) void kC(
    const float* __restrict__ mid_ws,
    const float* __restrict__ Wout, const float* __restrict__ bout,
    const float* __restrict__ x, float* __restrict__ out)
{
  __shared__ float ml[128][68];
  const int blk = blockIdx.x;
  const int pt0 = blk << 6;
  const int b  = pt0 >> 13;
  const int n0 = pt0 & (NPTS - 1);

  for (int e = threadIdx.x; e < 64 * 128; e += 256) {
    int p = e >> 7, c = e & 127;
    ml[c][p] = mid_ws[(size_t)(pt0 + p) * 128 + c];
  }
  __syncthreads();

  const int pg = threadIdx.x & 15;
  const int oo = threadIdx.x >> 4;
  const int p0 = pg << 2;
  const int o0 = oo << 3;

  float acc[8][4] = {};
  for (int c = 0; c < 128; ++c) {
    const float4 mv = *reinterpret_cast<const float4*>(&ml[c][p0]);
#pragma unroll
    for (int jj = 0; jj < 8; ++jj) {
      float wv = Wout[(o0 + jj) * 128 + c];
      acc[jj][0] += wv * mv.x;
      acc[jj][1] += wv * mv.y;
      acc[jj][2] += wv * mv.z;
      acc[jj][3] += wv * mv.w;
    }
  }

#pragma unroll
  for (int jj = 0; jj < 8; ++jj) {
    int o = o0 + jj;
    float bo = bout[o];
#pragma unroll
    for (int pp = 0; pp < 4; ++pp) {
      size_t gi = (size_t)(b * 128 + o) * NPTS + (n0 + p0 + pp);
      out[gi] = acc[jj][pp] + bo + x[gi];
    }
  }
}

extern "C" void kernel_launch(void* const* d_in, const int* in_sizes, int n_in,
                              void* d_out, int out_size, void* d_ws, size_t ws_size,
                              hipStream_t stream)
{
  const float* x    = (const float*)d_in[0];
  const int*   idx  = (const int*)  d_in[1];
  const float* W1   = (const float*)d_in[2];
  const float* b1   = (const float*)d_in[3];
  const float* W2   = (const float*)d_in[4];
  const float* b2   = (const float*)d_in[5];
  const float* W3   = (const float*)d_in[6];
  const float* b3   = (const float*)d_in[7];
  const float* Ww1  = (const float*)d_in[8];
  const float* Ww2  = (const float*)d_in[9];
  const float* bw2  = (const float*)d_in[10];
  const float* Wout = (const float*)d_in[11];
  const float* bout = (const float*)d_in[12];

  float* out     = (float*)d_out;
  __half* Yg     = (__half*)d_ws;                                   // 12.58 MB
  float* mid     = (float*)((char*)d_ws + (size_t)TOTPTS * 192 * 2);// 16.78 MB
  float* Ww2T    = mid + (size_t)TOTPTS * 128;                      // 16 KB
  float* V       = Ww2T + 16 * 256;                                 // 37.75 MB
  float* out_idx = out + (size_t)NB * 128 * NPTS;

  kT<<<1,    256, 0, stream>>>(Ww2, Ww2T);
  kA<<<512,  256, 0, stream>>>(x, W1, b1, W2, b2, W3, b3, Yg);
  kV<<<512,  256, 0, stream>>>(Yg, Ww1, V);
  kB<<<8192, 256, 0, stream>>>(V, Yg, idx, Ww2T, bw2, mid, out_idx);
  kC<<<512,  256, 0, stream>>>(mid, Wout, bout, x, out);
}

// Round 5
// 121.937 us; speedup vs baseline: 2.1627x; 1.3480x over previous
//
#include <hip/hip_runtime.h>
#include <hip/hip_fp16.h>

#define NPTS    8192
#define NB      4
#define TOTPTS  32768
#define VSTRIDE 288   // floats per point in V: [u(16) | v(kk*16+m, 256) | pad(16)]
// Yg layout per point (192 halves):
//   [0:32)   relu(x1)   [32:64) relu(y2)   (kV inputs, fp16)
//   [64:192) y3 interleaved: half 64+2c = y3[c], 64+2c+1 = y3[c+64]

typedef __attribute__((ext_vector_type(8))) short bf16x8;
typedef __attribute__((ext_vector_type(4))) float f32x4;

static __device__ __forceinline__ ushort f2bf(float f) {
  unsigned u = __float_as_uint(f);
  unsigned r = (u + 0x7FFFu + ((u >> 16) & 1u)) >> 16;
  return (ushort)r;
}

// ---------------- kTW: one-time weight prep -------------------------------------------
// Ww2T[16][256]; Wb = bf16 A-frags of Wcat[192][128]; Woutb = bf16 A-frags of Wout;
// bcat[192] = concatenated biases.
__global__ __launch_bounds__(256) void kTW(
    const float* __restrict__ W1, const float* __restrict__ W2, const float* __restrict__ W3,
    const float* __restrict__ b1, const float* __restrict__ b2, const float* __restrict__ b3,
    const float* __restrict__ Ww2, const float* __restrict__ Wout,
    float* __restrict__ Ww2T, ushort* __restrict__ Wb, ushort* __restrict__ Woutb,
    float* __restrict__ bcat)
{
  const int t = threadIdx.x;
#pragma unroll
  for (int q = 0; q < 16; ++q) Ww2T[q * 256 + t] = Ww2[t * 16 + q];

  for (int e = t; e < 24576; e += 256) {       // Wb: [mt<12][kt<4][lane<64][j<8]
    int j = e & 7, l = (e >> 3) & 63, kt = (e >> 9) & 3, mt = e >> 11;
    int row = mt * 16 + (l & 15);
    int k = kt * 32 + (l >> 4) * 8 + j;
    float v;
    if (row < 32)      v = W1[row * 128 + k];
    else if (row < 64) v = W2[(row - 32) * 128 + k];
    else               v = W3[(row - 64) * 128 + k];
    Wb[e] = f2bf(v);
  }
  for (int e = t; e < 16384; e += 256) {       // Woutb: [mt<8][kt<4][lane<64][j<8]
    int j = e & 7, l = (e >> 3) & 63, kt = (e >> 9) & 3, mt = e >> 11;
    int row = mt * 16 + (l & 15);
    int k = kt * 32 + (l >> 4) * 8 + j;
    Woutb[e] = f2bf(Wout[row * 128 + k]);
  }
  if (t < 192) {
    float v;
    if (t < 32)      v = b1[t];
    else if (t < 64) v = b2[t - 32];
    else             v = b3[t - 64];
    bcat[t] = v;
  }
}

// ---------------- kA: Yg = fused 1x1 convs of relu(x), bf16 MFMA ----------------------
__global__ __launch_bounds__(256) void kA(
    const float* __restrict__ x, const ushort* __restrict__ Wb,
    const float* __restrict__ bcat, __half* __restrict__ Yg)
{
  __shared__ ushort blds[8192];                 // B-frags: [w<4][kt<4][lane<64][j<8]
  __shared__ __half yst[64][200];

  const int t = threadIdx.x;
  const int blk = blockIdx.x;                   // 512
  const int b  = blk >> 7;
  const int n0 = (blk & 127) << 6;
  const float* xb = x + (size_t)b * 128 * NPTS;

  // stage relu(x) -> bf16 B-fragments (coalesced reads)
#pragma unroll
  for (int i = 0; i < 32; ++i) {
    int e = t + 256 * i;                        // 8192 = 128 k * 64 pts
    int k = e >> 6, p = e & 63;
    float v = fmaxf(xb[(size_t)k * NPTS + n0 + p], 0.f);
    int lane = ((k & 31) >> 3) * 16 + (p & 15);
    int flat = (((p >> 4) * 4 + (k >> 5)) * 64 + lane) * 8 + (k & 7);
    blds[flat] = f2bf(v);
  }
  __syncthreads();

  const int w = t >> 6, l = t & 63;
  bf16x8 bfr[4];
#pragma unroll
  for (int kt = 0; kt < 4; ++kt)
    bfr[kt] = *reinterpret_cast<const bf16x8*>(&blds[((w * 4 + kt) * 64 + l) * 8]);

  const int pt = 16 * w + (l & 15);
  const int rbase = (l >> 4) * 4;
#pragma unroll
  for (int mt = 0; mt < 12; ++mt) {
    f32x4 acc = {0.f, 0.f, 0.f, 0.f};
#pragma unroll
    for (int kt = 0; kt < 4; ++kt) {
      bf16x8 a = *reinterpret_cast<const bf16x8*>(Wb + ((size_t)(mt * 4 + kt) * 64 + l) * 8);
      acc = __builtin_amdgcn_mfma_f32_16x16x32_bf16(a, bfr[kt], acc, 0, 0, 0);
    }
#pragma unroll
    for (int r = 0; r < 4; ++r) {
      int c = mt * 16 + rbase + r;
      float v = acc[r] + bcat[c];
      int mc;
      if (c < 64) { v = fmaxf(v, 0.f); mc = c; }
      else { int cc = c - 64; mc = 64 + ((cc < 64) ? 2 * cc : 2 * (cc - 64) + 1); }
      yst[pt][mc] = __float2half(v);
    }
  }
  __syncthreads();

  const unsigned* ys32 = (const unsigned*)yst;  // rows of 100 uints
  unsigned* Yg32 = (unsigned*)(Yg + (size_t)(b * NPTS + n0) * 192);
  for (int v = t; v < 64 * 96; v += 256) {
    int p = v / 96, cu = v - p * 96;
    Yg32[p * 96 + cu] = ys32[p * 100 + cu];
  }
}

// ---------------- kV: per-point u,v precompute ----------------------------------------
__global__ __launch_bounds__(256) void kV(
    const __half* __restrict__ Yg, const float* __restrict__ Ww1,
    float* __restrict__ V)
{
  __shared__ float a_lds[64][66];
  __shared__ float v_lds[64][148];
  const int t = threadIdx.x;
  const int w = __builtin_amdgcn_readfirstlane(t >> 6);
  const int l = t & 63;
  const int pt0 = blockIdx.x * 64;

  const unsigned* Yg32 = (const unsigned*)Yg + (size_t)pt0 * 96;
#pragma unroll
  for (int i = 0; i < 8; ++i) {
    int e = t + 256 * i;
    int p = e >> 5, cu = e & 31;
    unsigned uu = Yg32[(size_t)p * 96 + cu];
    __half2 hv = *reinterpret_cast<const __half2*>(&uu);
    a_lds[p][2 * cu]     = __low2float(hv);
    a_lds[p][2 * cu + 1] = __high2float(hv);
  }
  __syncthreads();

  const int p = l;
  {
    float acc[4] = {};
    for (int c = 0; c < 32; ++c) {
      float a = a_lds[p][c];
#pragma unroll
      for (int e = 0; e < 4; ++e)
        acc[e] = fmaf(Ww1[(4 * w + e) * 544 + c], a, acc[e]);
    }
#pragma unroll
    for (int e = 0; e < 4; ++e) v_lds[p][4 * w + e] = acc[e];
  }

  float ay[32];
#pragma unroll
  for (int o = 0; o < 32; ++o) ay[o] = a_lds[p][32 + o];

  {
    float acc[8][4] = {};
#pragma unroll 4
    for (int o = 0; o < 32; ++o) {
      float a = ay[o];
#pragma unroll
      for (int kk = 0; kk < 8; ++kk)
#pragma unroll
        for (int e = 0; e < 4; ++e)
          acc[kk][e] = fmaf(Ww1[(4 * w + e) * 544 + 32 + o * 16 + kk], a, acc[kk][e]);
    }
#pragma unroll
    for (int kk = 0; kk < 8; ++kk)
#pragma unroll
      for (int e = 0; e < 4; ++e)
        v_lds[p][16 + kk * 16 + 4 * w + e] = acc[kk][e];
  }
  __syncthreads();
#pragma unroll
  for (int i = 0; i < 36; ++i) {
    int e = t + 256 * i;                 // 9216 = 64*144
    int pp = e / 144, f = e - pp * 144;
    V[(size_t)(pt0 + pp) * VSTRIDE + f] = v_lds[pp][f];
  }
  __syncthreads();

  {
    float acc[8][4] = {};
#pragma unroll 4
    for (int o = 0; o < 32; ++o) {
      float a = ay[o];
#pragma unroll
      for (int k2 = 0; k2 < 8; ++k2)
#pragma unroll
        for (int e = 0; e < 4; ++e)
          acc[k2][e] = fmaf(Ww1[(4 * w + e) * 544 + 32 + o * 16 + 8 + k2], a, acc[k2][e]);
    }
#pragma unroll
    for (int k2 = 0; k2 < 8; ++k2)
#pragma unroll
      for (int e = 0; e < 4; ++e)
        v_lds[p][k2 * 16 + 4 * w + e] = acc[k2][e];
  }
  __syncthreads();
#pragma unroll
  for (int i = 0; i < 32; ++i) {
    int e = t + 256 * i;                 // 8192 = 64*128
    int pp = e >> 7, f = e & 127;
    V[(size_t)(pt0 + pp) * VSTRIDE + 144 + f] = v_lds[pp][f];
  }
}

// ---------------- kB: gather + attention weights + weighted sum (1 wave / point) ------
__global__ __launch_bounds__(256) void kB(
    const float* __restrict__ V, const __half* __restrict__ Yg,
    const int* __restrict__ idx, const float* __restrict__ Ww2T,
    const float* __restrict__ bw2, ushort* __restrict__ midb,
    float* __restrict__ out_idx)
{
  __shared__ float wcs[4][272];
  __shared__ float hs[4][16];

  const int w = threadIdx.x >> 6, l = threadIdx.x & 63;
  const int pt = blockIdx.x * 4 + w;
  const int bbase = pt & ~(NPTS - 1);
  const int kk = l >> 2, j = l & 3;

  const int idxv = idx[(size_t)pt * 16 + (l & 15)];
  if (l < 16) out_idx[(size_t)pt * 16 + l] = (float)idxv;

  // h = relu(u + sum_kk v[nb_kk])   (u added once, by kk==0 lanes only)
  const float4* V4 = (const float4*)V;
  int nb = __shfl(idxv, kk);
  float4 h4 = V4[(size_t)(bbase + nb) * 72 + 4 + kk * 4 + j];
  if (kk == 0) {
    const float4 uu = V4[(size_t)pt * 72 + j];
    h4.x += uu.x; h4.y += uu.y; h4.z += uu.z; h4.w += uu.w;
  }
#pragma unroll
  for (int s = 4; s < 64; s <<= 1) {
    h4.x += __shfl_xor(h4.x, s);
    h4.y += __shfl_xor(h4.y, s);
    h4.z += __shfl_xor(h4.z, s);
    h4.w += __shfl_xor(h4.w, s);
  }
  if (l < 4) {
    hs[w][4 * l + 0] = fmaxf(h4.x, 0.f);
    hs[w][4 * l + 1] = fmaxf(h4.y, 0.f);
    hs[w][4 * l + 2] = fmaxf(h4.z, 0.f);
    hs[w][4 * l + 3] = fmaxf(h4.w, 0.f);
  }

  // y3 gather -> registers
  __half2 y3v[16];
#pragma unroll
  for (int k2 = 0; k2 < 16; ++k2) {
    int nb2 = __shfl(idxv, k2);
    y3v[k2] = *reinterpret_cast<const __half2*>(
        Yg + (size_t)(bbase + nb2) * 192 + 64 + 2 * l);
  }

  // wc[r] = bw2[r] + Ww2T[:,r] . h
#pragma unroll
  for (int u2 = 0; u2 < 2; ++u2) {
    int r = 2 * l + 128 * u2;
    float2 s2 = *reinterpret_cast<const float2*>(bw2 + r);
#pragma unroll
    for (int q = 0; q < 16; ++q) {
      const float2 wv = *reinterpret_cast<const float2*>(Ww2T + q * 256 + r);
      float hq = hs[w][q];
      s2.x = fmaf(wv.x, hq, s2.x);
      s2.y = fmaf(wv.y, hq, s2.y);
    }
    int g = r >> 4, jj = r & 15;
    wcs[w][g * 17 + jj]     = s2.x;
    wcs[w][g * 17 + jj + 1] = s2.y;
  }

  // mid[c] = relu(sum_k wc[c&15][k] * y3[k][c])  -> bf16
  const float* wrow = &wcs[w][(l & 15) * 17];
  float m0 = 0.f, m1 = 0.f;
#pragma unroll
  for (int q = 0; q < 16; ++q) {
    float2 y = __half22float2(y3v[q]);
    m0 = fmaf(wrow[q], y.x, m0);
    m1 = fmaf(wrow[q], y.y, m1);
  }
  midb[(size_t)pt * 128 + l]      = f2bf(fmaxf(m0, 0.f));
  midb[(size_t)pt * 128 + 64 + l] = f2bf(fmaxf(m1, 0.f));
}

// ---------------- kC: out = Wout @ mid + bout + x, bf16 MFMA --------------------------
__global__ __launch_bounds__(256) void kC(
    const ushort* __restrict__ midb, const ushort* __restrict__ Woutb,
    const float* __restrict__ bout,
    const float* __restrict__ x, float* __restrict__ out)
{
  __shared__ ushort blds[8192];
  __shared__ float ml[128][68];

  const int t = threadIdx.x;
  const int pt0 = blockIdx.x << 6;
  const int b  = pt0 >> 13;
  const int n0 = pt0 & (NPTS - 1);

  const unsigned* mid32 = (const unsigned*)midb;
  unsigned* blds32 = (unsigned*)blds;
#pragma unroll
  for (int i = 0; i < 16; ++i) {
    int e = t + 256 * i;                        // 4096 uints = 64 pts * 64 ch-pairs
    int u = e & 63, p = e >> 6;
    unsigned val = mid32[(size_t)(pt0 + p) * 64 + u];
    int lane = ((u & 15) >> 2) * 16 + (p & 15);
    int fl = (((p >> 4) * 4 + (u >> 4)) * 64 + lane) * 4 + (u & 3);
    blds32[fl] = val;
  }
  __syncthreads();

  const int w = t >> 6, l = t & 63;
  bf16x8 bfr[4];
#pragma unroll
  for (int kt = 0; kt < 4; ++kt)
    bfr[kt] = *reinterpret_cast<const bf16x8*>(&blds[((w * 4 + kt) * 64 + l) * 8]);

  const int rbase = (l >> 4) * 4;
  const int pl = 16 * w + (l & 15);
#pragma unroll
  for (int mt = 0; mt < 8; ++mt) {
    f32x4 acc = {0.f, 0.f, 0.f, 0.f};
#pragma unroll
    for (int kt = 0; kt < 4; ++kt) {
      bf16x8 a = *reinterpret_cast<const bf16x8*>(Woutb + ((size_t)(mt * 4 + kt) * 64 + l) * 8);
      acc = __builtin_amdgcn_mfma_f32_16x16x32_bf16(a, bfr[kt], acc, 0, 0, 0);
    }
#pragma unroll
    for (int r = 0; r < 4; ++r)
      ml[mt * 16 + rbase + r][pl] = acc[r];
  }
  __syncthreads();

  for (int e = t; e < 8192; e += 256) {
    int c = e >> 6, p = e & 63;
    size_t gi = (size_t)(b * 128 + c) * NPTS + n0 + p;
    out[gi] = ml[c][p] + bout[c] + x[gi];
  }
}

extern "C" void kernel_launch(void* const* d_in, const int* in_sizes, int n_in,
                              void* d_out, int out_size, void* d_ws, size_t ws_size,
                              hipStream_t stream)
{
  const float* x    = (const float*)d_in[0];
  const int*   idx  = (const int*)  d_in[1];
  const float* W1   = (const float*)d_in[2];
  const float* b1   = (const float*)d_in[3];
  const float* W2   = (const float*)d_in[4];
  const float* b2   = (const float*)d_in[5];
  const float* W3   = (const float*)d_in[6];
  const float* b3   = (const float*)d_in[7];
  const float* Ww1  = (const float*)d_in[8];
  const float* Ww2  = (const float*)d_in[9];
  const float* bw2  = (const float*)d_in[10];
  const float* Wout = (const float*)d_in[11];
  const float* bout = (const float*)d_in[12];

  float* out     = (float*)d_out;
  float* out_idx = out + (size_t)NB * 128 * NPTS;

  char* wsp = (char*)d_ws;
  __half* Yg    = (__half*)wsp;  wsp += (size_t)TOTPTS * 192 * 2;   // 12.58 MB
  ushort* midb  = (ushort*)wsp;  wsp += (size_t)TOTPTS * 128 * 2;   //  8.39 MB
  float*  V     = (float*)wsp;   wsp += (size_t)TOTPTS * VSTRIDE * 4; // 37.75 MB
  float*  Ww2T  = (float*)wsp;   wsp += 4096 * 4;
  ushort* Wb    = (ushort*)wsp;  wsp += 24576 * 2;
  ushort* Woutb = (ushort*)wsp;  wsp += 16384 * 2;
  float*  bcat  = (float*)wsp;   wsp += 192 * 4;

  kTW<<<1,   256, 0, stream>>>(W1, W2, W3, b1, b2, b3, Ww2, Wout, Ww2T, Wb, Woutb, bcat);
  kA<<<512,  256, 0, stream>>>(x, Wb, bcat, Yg);
  kV<<<512,  256, 0, stream>>>(Yg, Ww1, V);
  kB<<<8192, 256, 0, stream>>>(V, Yg, idx, Ww2T, bw2, midb, out_idx);
  kC<<<512,  256, 0, stream>>>(midb, Woutb, bout, x, out);
}